// Round 3
// baseline (725.770 us; speedup 1.0000x reference)
//
#include <hip/hip_runtime.h>
#include <hip/hip_bf16.h>

// VGG16 ROI head: roi_pool -> fc6(relu) -> fc7(relu) -> {cls, score}
// Weight-streaming memory-bound (fc6 W = 411 MB fp32). bf16 MFMA 16x16x32.
// R2: LDS-staged GEMM. Stage W fp32->bf16 once per tile (convert-on-write),
// transposed LDS layout [64 n][SK=34 k] so B-fragments are k-contiguous dword
// reads. Double-buffered LDS, 1 barrier/step, global prefetch 2 steps ahead,
// loop unrolled x2 so all buffer indices are compile-time constants.
// R3: latency-bound theory — raise resident blocks/CU from 2 to 4 by using
// more k-slabs (fc6 28, fc7 16), gated on ws_size with fallback to the old
// 8-slab layout. GEMM body unchanged.
// R4/R5: identical resubmits (three broker timeouts; R3 never measured).

typedef short short8 __attribute__((ext_vector_type(8)));   // 8 x bf16 bits
typedef float f32x4 __attribute__((ext_vector_type(4)));
typedef int   int4v __attribute__((ext_vector_type(4)));

#define TN 64
#define SK 34      // LDS k-stride in shorts (32 + 2 pad: breaks bank aliasing)

static __device__ inline unsigned bfround(float f) {   // fp32 -> bf16 bits (round-half-up)
    return __builtin_bit_cast(unsigned, f) + 0x8000u;
}
static __device__ inline short f2bf(float f) { return (short)(bfround(f) >> 16); }

// ---------------- ROI max-pool: x (1,512,37,50) -> A (128, 25088) bf16 ----------------
__global__ void pool_kernel(const float* __restrict__ x, const float* __restrict__ rois,
                            const int* __restrict__ ridx, short* __restrict__ A) {
    const int r = blockIdx.x;
    const int y1 = (int)floorf(rois[r * 4 + 0] * 0.0625f);
    const int x1 = (int)floorf(rois[r * 4 + 1] * 0.0625f);
    const int y2 = (int)floorf(rois[r * 4 + 2] * 0.0625f);
    const int x2 = (int)floorf(rois[r * 4 + 3] * 0.0625f);
    const int h = y2 - y1 + 1, w = x2 - x1 + 1;
    const float* feat = x + (size_t)ridx[r] * (512 * 37 * 50);
    for (int t = blockIdx.y * 256 + threadIdx.x; t < 25088; t += 2048) {
        const int c = t / 49, b = t % 49, i = b / 7, j = b % 7;
        const int ys = y1 + (i * h) / 7, ye = y1 + ((i + 1) * h + 6) / 7;
        const int xs = x1 + (j * w) / 7, xe = x1 + ((j + 1) * w + 6) / 7;
        const float* f = feat + c * 1850;
        float m = -1e30f;
        for (int yy = ys; yy < ye; yy++)
            for (int xx = xs; xx < xe; xx++)
                m = fmaxf(m, f[yy * 50 + xx]);
        A[(size_t)r * 25088 + t] = f2bf(m);
    }
}

// ---------------- pack w_cls (4096x84) + w_score (4096x21) -> whd (4096x128) ----------------
__global__ void build_whd(const float* __restrict__ wc, const float* __restrict__ wsc,
                          float* __restrict__ whd) {
    const int idx = blockIdx.x * 256 + threadIdx.x;   // < 4096*128
    const int k = idx >> 7, n = idx & 127;
    float v = 0.f;
    if (n < 84) v = wc[k * 84 + n];
    else if (n < 105) v = wsc[k * 21 + (n - 84)];
    whd[idx] = v;
}

// ---------------- M=128 GEMM: part[slab] = A(128xK bf16) @ W(KxN fp32) ----------------
// block: 256 thr (4 waves). Block tile: 128 m x 64 n. K-step = 32.
// Staging thread map: kp = tid>>4 (k-pair 0..15 -> k = 2kp,2kp+1), nb = (tid&15)*4.
// Each thread: 2 x float4 (rows k,k+1; cols nb..nb+3), convert, pack k-pairs
// into dwords, write transposed LDS [n][k].  Requires steps even and >= 4.
__global__ __launch_bounds__(256, 4)
void gemm128(const short* __restrict__ A, const float* __restrict__ W,
             float* __restrict__ part, int K, int N, int kchunk) {
    __shared__ short lds[2][TN * SK];

    const int tid = threadIdx.x;
    const int lane = tid & 63, wave = tid >> 6;
    const int l15 = lane & 15, quad = lane >> 4;
    const int n_base = blockIdx.x * TN;
    const int kb = blockIdx.y * kchunk;
    const int m0 = wave * 32;
    const int steps = kchunk >> 5;

    const int kp = tid >> 4;          // 0..15
    const int nb = (tid & 15) * 4;    // 0,4,...,60
    const float* gW = W + (size_t)(kb + 2 * kp) * N + n_base + nb;
    const short* gA = A + (size_t)(m0 + l15) * K + kb + quad * 8;

    f32x4 acc[2][4] = {};
    f32x4 wset[2][2];    // [stage][k-row of pair]
    short8 aset[2][2];   // [stage][m-tile]

    auto wload = [&](int s, int c) {
        const float* p = gW + (size_t)s * 32 * N;
        wset[c][0] = *(const f32x4*)p;
        wset[c][1] = *(const f32x4*)(p + N);
    };
    auto aload = [&](int s, int c) {
        const short* p = gA + (size_t)s * 32;
        aset[c][0] = *(const short8*)p;
        aset[c][1] = *(const short8*)(p + (size_t)16 * K);
    };
    auto stage = [&](int c, int buf) {   // convert wset[c] -> lds[buf]
        unsigned* dst = (unsigned*)&lds[buf][0];
#pragma unroll
        for (int i = 0; i < 4; i++) {
            unsigned lo = bfround(wset[c][0][i]) >> 16;
            unsigned hi = bfround(wset[c][1][i]) & 0xffff0000u;
            dst[((nb + i) * SK + 2 * kp) >> 1] = lo | hi;
        }
    };

    // prologue: stages 0,1 in flight; stage 0 into buf 0
    wload(0, 0); wload(1, 1);
    aload(0, 0); aload(1, 1);
    stage(0, 0);

    for (int s = 0; s < steps; s += 2) {
#pragma unroll
        for (int half = 0; half < 2; half++) {
            const int ss = s + half;
            const int C = half;          // compile-time 0/1
            if (ss + 2 < steps) wload(ss + 2, C);
            __syncthreads();
            const short* buf = &lds[C][0];
#pragma unroll
            for (int fn = 0; fn < 4; fn++) {
                const int* src = (const int*)(buf + (fn * 16 + l15) * SK + quad * 8);
                int4v t;
                t[0] = src[0]; t[1] = src[1]; t[2] = src[2]; t[3] = src[3];
                short8 bfr = __builtin_bit_cast(short8, t);
                acc[0][fn] = __builtin_amdgcn_mfma_f32_16x16x32_bf16(aset[C][0], bfr, acc[0][fn], 0, 0, 0);
                acc[1][fn] = __builtin_amdgcn_mfma_f32_16x16x32_bf16(aset[C][1], bfr, acc[1][fn], 0, 0, 0);
            }
            if (ss + 2 < steps) aload(ss + 2, C);
            if (ss + 1 < steps) stage(C ^ 1, C ^ 1);
        }
    }

    float* out = part + (size_t)blockIdx.y * 128 * N;
#pragma unroll
    for (int t = 0; t < 2; t++)
#pragma unroll
        for (int fn = 0; fn < 4; fn++)
#pragma unroll
            for (int r = 0; r < 4; r++) {
                const int row = m0 + 16 * t + quad * 4 + r;
                const int col = n_base + fn * 16 + l15;
                out[(size_t)row * N + col] = acc[t][fn][r];
            }
}

// ---------------- slab-reduce + bias + relu -> bf16 activations ----------------
__global__ void reduce_fc(const float* __restrict__ part, const float* __restrict__ bias,
                          short* __restrict__ out, int N, int nslabs) {
    const int idx = blockIdx.x * 256 + threadIdx.x;   // < 128*N
    const int n = idx % N;
    float s = bias[n];
    for (int sl = 0; sl < nslabs; sl++) s += part[(size_t)sl * 128 * N + idx];
    s = fmaxf(s, 0.f);
    out[idx] = f2bf(s);
}

// ---------------- heads slab-reduce + bias -> d_out (cls 128x84 | score 128x21) ----------------
__global__ void reduce_heads(const float* __restrict__ part, const float* __restrict__ bc,
                             const float* __restrict__ bsc, float* __restrict__ out) {
    const int idx = blockIdx.x * 256 + threadIdx.x;
    if (idx >= 128 * 105) return;
    const int m = idx / 105, n = idx % 105;
    float s = 0.f;
    for (int sl = 0; sl < 32; sl++) s += part[sl * (128 * 128) + m * 128 + n];
    if (n < 84) out[m * 84 + n] = s + bc[n];
    else out[128 * 84 + m * 21 + (n - 84)] = s + bsc[n - 84];
}

extern "C" void kernel_launch(void* const* d_in, const int* in_sizes, int n_in,
                              void* d_out, int out_size, void* d_ws, size_t ws_size,
                              hipStream_t stream) {
    const float* x    = (const float*)d_in[0];
    const float* rois = (const float*)d_in[1];
    const int*   ridx = (const int*)d_in[2];
    const float* w6   = (const float*)d_in[3];
    const float* b6   = (const float*)d_in[4];
    const float* w7   = (const float*)d_in[5];
    const float* b7   = (const float*)d_in[6];
    const float* wc   = (const float*)d_in[7];
    const float* bc   = (const float*)d_in[8];
    const float* wsc  = (const float*)d_in[9];
    const float* bsc  = (const float*)d_in[10];
    float* out = (float*)d_out;

    char* base = (char*)d_ws;
    short* Apool = (short*)base;                         // 128*25088*2 = 6,422,528 B
    float* whd   = (float*)(base + 6422528);             // 4096*128*4  = 2,097,152 B
    short* fc6b  = (short*)(base + 8519680);             // 128*4096*2  = 1,048,576 B
    short* fc7b  = (short*)(base + 9568256);             // 128*4096*2  = 1,048,576 B
    float* slabs = (float*)(base + 10616832);            // nslabs*128*4096*4 each
    const size_t slab_base = 10616832;
    const size_t slab_bytes = (size_t)128 * 4096 * 4;    // 2 MB per slab

    // fc6 slab count: 28 -> grid 1792 (7 blocks/CU queued, 4 resident = VGPR cap);
    // kchunk must give even steps (unroll x2): 25088/28=896 (28 steps),
    // 25088/14=1792 (56), 25088/8=3136 (98).
    int ns6 = 8, ks6 = 3136;
    if (ws_size >= slab_base + 28 * slab_bytes)      { ns6 = 28; ks6 = 896; }
    else if (ws_size >= slab_base + 14 * slab_bytes) { ns6 = 14; ks6 = 1792; }
    int ns7 = 8, ks7 = 512;
    if (ws_size >= slab_base + 16 * slab_bytes)      { ns7 = 16; ks7 = 256; }

    pool_kernel<<<dim3(128, 8), 256, 0, stream>>>(x, rois, ridx, Apool);
    build_whd<<<2048, 256, 0, stream>>>(wc, wsc, whd);

    // fc6: K=25088, N=4096
    gemm128<<<dim3(64, ns6), 256, 0, stream>>>(Apool, w6, slabs, 25088, 4096, ks6);
    reduce_fc<<<2048, 256, 0, stream>>>(slabs, b6, fc6b, 4096, ns6);

    // fc7: K=4096, N=4096
    gemm128<<<dim3(64, ns7), 256, 0, stream>>>(fc6b, w7, slabs, 4096, 4096, ks7);
    reduce_fc<<<2048, 256, 0, stream>>>(slabs, b7, fc7b, 4096, ns7);

    // heads: K=4096, N=128 (padded), 32 k-slabs (kchunk 128 -> 4 steps), 64 blocks
    gemm128<<<dim3(2, 32), 256, 0, stream>>>(fc7b, whd, slabs, 4096, 128, 128);
    reduce_heads<<<53, 256, 0, stream>>>(slabs, bc, bsc, out);
}

// Round 7
// 699.171 us; speedup vs baseline: 1.0380x; 1.0380x over previous
//
#include <hip/hip_runtime.h>
#include <hip/hip_bf16.h>

// VGG16 ROI head: roi_pool -> fc6(relu) -> fc7(relu) -> {cls, score}
// Weight-streaming memory-bound (fc6 W = 411 MB fp32). bf16 MFMA 16x16x32.
// R2: LDS-staged GEMM, transposed W layout [n][SK=34 k], double-buffered,
//     2-deep register prefetch, 1 barrier/half, unroll x2.
// R3: more k-slabs (fc6 28, fc7 16) for 4 resident blocks/CU -> NULL result
//     (701 -> 726 us): not latency-bound. Profile note: all top-5 dispatches
//     were harness fills (~250 us, 1.64 GB) => every kernel here is < 248 us;
//     fc6 gemm already streams W at >= 1.7 TB/s. Next profile must compare
//     sum(own dispatches) vs total to see if the poison-fill is timed.
// R6: ingress-amplification theory. At TN=64 each block-step moves 8KB W +
//     8KB A (A re-read by all 64 n-blocks = 411 MB from L2/L3) -> 2.0 B
//     ingress per W-byte. New: 512-thread blocks, TN=128 (8 waves = 4m x 2n),
//     A staged in LDS once per step (8KB) shared by both n-groups ->
//     amplification 1.5. Predict fc6 dispatch -20-25%.
// R7/R8/R9: identical resubmits (broker timeouts; R6 never measured).

typedef short short8 __attribute__((ext_vector_type(8)));   // 8 x bf16 bits
typedef float f32x4 __attribute__((ext_vector_type(4)));
typedef int   int4v __attribute__((ext_vector_type(4)));

#define TN 128
#define SK 34      // W LDS k-stride in shorts (32 + 2 pad)
#define SKA 40     // A LDS k-stride in shorts (32 + 8 pad, keeps b128 16B-aligned)

static __device__ inline unsigned bfround(float f) {   // fp32 -> bf16 bits (round-half-up)
    return __builtin_bit_cast(unsigned, f) + 0x8000u;
}
static __device__ inline short f2bf(float f) { return (short)(bfround(f) >> 16); }

// ---------------- ROI max-pool: x (1,512,37,50) -> A (128, 25088) bf16 ----------------
__global__ void pool_kernel(const float* __restrict__ x, const float* __restrict__ rois,
                            const int* __restrict__ ridx, short* __restrict__ A) {
    const int r = blockIdx.x;
    const int y1 = (int)floorf(rois[r * 4 + 0] * 0.0625f);
    const int x1 = (int)floorf(rois[r * 4 + 1] * 0.0625f);
    const int y2 = (int)floorf(rois[r * 4 + 2] * 0.0625f);
    const int x2 = (int)floorf(rois[r * 4 + 3] * 0.0625f);
    const int h = y2 - y1 + 1, w = x2 - x1 + 1;
    const float* feat = x + (size_t)ridx[r] * (512 * 37 * 50);
    for (int t = blockIdx.y * 256 + threadIdx.x; t < 25088; t += 2048) {
        const int c = t / 49, b = t % 49, i = b / 7, j = b % 7;
        const int ys = y1 + (i * h) / 7, ye = y1 + ((i + 1) * h + 6) / 7;
        const int xs = x1 + (j * w) / 7, xe = x1 + ((j + 1) * w + 6) / 7;
        const float* f = feat + c * 1850;
        float m = -1e30f;
        for (int yy = ys; yy < ye; yy++)
            for (int xx = xs; xx < xe; xx++)
                m = fmaxf(m, f[yy * 50 + xx]);
        A[(size_t)r * 25088 + t] = f2bf(m);
    }
}

// ---------------- pack w_cls (4096x84) + w_score (4096x21) -> whd (4096x128) ----------------
__global__ void build_whd(const float* __restrict__ wc, const float* __restrict__ wsc,
                          float* __restrict__ whd) {
    const int idx = blockIdx.x * 256 + threadIdx.x;   // < 4096*128
    const int k = idx >> 7, n = idx & 127;
    float v = 0.f;
    if (n < 84) v = wc[k * 84 + n];
    else if (n < 105) v = wsc[k * 21 + (n - 84)];
    whd[idx] = v;
}

// ---------------- M=128 GEMM: part[slab] = A(128xK bf16) @ W(KxN fp32) ----------------
// block: 512 thr (8 waves = 4 m-groups x 2 n-groups). Tile 128m x 128n, K-step 32.
// W staging: kp = tid>>5 (k-pair), nb = (tid&31)*4. 2 x float4 per thread
// (rows 2kp,2kp+1), convert fp32->bf16, pack k-pairs to dwords, write
// transposed LDS [n][SK].  A staging: m = tid>>2, kq = tid&3: one short8 from
// A[m][kb+s*32+kq*8] -> LDS [m][SKA] (row-major, b128-aligned).
// Requires steps even and >= 4.
__global__ __launch_bounds__(512, 4)
void gemm128(const short* __restrict__ A, const float* __restrict__ W,
             float* __restrict__ part, int K, int N, int kchunk) {
    __shared__ short ldsW[2][TN * SK];     // 2 x 8704 B
    __shared__ short ldsA[2][128 * SKA];   // 2 x 10240 B

    const int tid = threadIdx.x;
    const int lane = tid & 63, wave = tid >> 6;
    const int l15 = lane & 15, quad = lane >> 4;
    const int wm = wave & 3;              // m-group: rows wm*32..+31
    const int wn = wave >> 2;             // n-group: cols wn*64..+63
    const int n_base = blockIdx.x * TN;
    const int kb = blockIdx.y * kchunk;
    const int steps = kchunk >> 5;

    // W staging map
    const int kp = tid >> 5;              // 0..15
    const int nb = (tid & 31) * 4;        // 0,4,...,124
    const float* gW = W + (size_t)(kb + 2 * kp) * N + n_base + nb;
    // A staging map
    const int am = tid >> 2;              // 0..127
    const int kq = tid & 3;               // k-octet
    const short* gA = A + (size_t)am * K + kb + kq * 8;

    f32x4 acc[2][4] = {};
    f32x4 wset[2][2];    // [stage][k-row of pair]
    short8 aglob[2];     // [stage]

    auto wload = [&](int s, int c) {
        const float* p = gW + (size_t)s * 32 * N;
        wset[c][0] = *(const f32x4*)p;
        wset[c][1] = *(const f32x4*)(p + N);
    };
    auto aload = [&](int s, int c) {
        aglob[c] = *(const short8*)(gA + (size_t)s * 32);
    };
    auto stage = [&](int c, int buf) {   // convert wset[c] -> ldsW[buf]; aglob[c] -> ldsA[buf]
        unsigned* dst = (unsigned*)&ldsW[buf][0];
#pragma unroll
        for (int i = 0; i < 4; i++) {
            unsigned lo = bfround(wset[c][0][i]) >> 16;
            unsigned hi = bfround(wset[c][1][i]) & 0xffff0000u;
            dst[(nb + i) * (SK / 2) + kp] = lo | hi;   // dword idx = (nb+i)*17 + kp
        }
        *(short8*)(&ldsA[buf][am * SKA + kq * 8]) = aglob[c];
    };

    // prologue: stages 0,1 in flight; stage 0 into buf 0
    wload(0, 0); wload(1, 1);
    aload(0, 0); aload(1, 1);
    stage(0, 0);

    for (int s = 0; s < steps; s += 2) {
#pragma unroll
        for (int half = 0; half < 2; half++) {
            const int ss = s + half;
            const int C = half;          // compile-time 0/1
            if (ss + 2 < steps) wload(ss + 2, C);
            __syncthreads();
            // A fragments for this wave's two 16-row m-subtiles
            const short* bufA = &ldsA[C][0];
            short8 afr0 = *(const short8*)(bufA + (wm * 32 + l15) * SKA + quad * 8);
            short8 afr1 = *(const short8*)(bufA + (wm * 32 + 16 + l15) * SKA + quad * 8);
            const short* bufW = &ldsW[C][0];
#pragma unroll
            for (int fn = 0; fn < 4; fn++) {
                const int* src = (const int*)(bufW + (wn * 64 + fn * 16 + l15) * SK + quad * 8);
                int4v t;
                t[0] = src[0]; t[1] = src[1]; t[2] = src[2]; t[3] = src[3];
                short8 bfr = __builtin_bit_cast(short8, t);
                acc[0][fn] = __builtin_amdgcn_mfma_f32_16x16x32_bf16(afr0, bfr, acc[0][fn], 0, 0, 0);
                acc[1][fn] = __builtin_amdgcn_mfma_f32_16x16x32_bf16(afr1, bfr, acc[1][fn], 0, 0, 0);
            }
            if (ss + 2 < steps) aload(ss + 2, C);
            if (ss + 1 < steps) stage(C ^ 1, C ^ 1);
        }
    }

    float* out = part + (size_t)blockIdx.y * 128 * N;
#pragma unroll
    for (int t = 0; t < 2; t++)
#pragma unroll
        for (int fn = 0; fn < 4; fn++)
#pragma unroll
            for (int r = 0; r < 4; r++) {
                const int row = wm * 32 + 16 * t + quad * 4 + r;
                const int col = n_base + wn * 64 + fn * 16 + l15;
                out[(size_t)row * N + col] = acc[t][fn][r];
            }
}

// ---------------- slab-reduce + bias + relu -> bf16 activations ----------------
__global__ void reduce_fc(const float* __restrict__ part, const float* __restrict__ bias,
                          short* __restrict__ out, int N, int nslabs) {
    const int idx = blockIdx.x * 256 + threadIdx.x;   // < 128*N
    const int n = idx % N;
    float s = bias[n];
    for (int sl = 0; sl < nslabs; sl++) s += part[(size_t)sl * 128 * N + idx];
    s = fmaxf(s, 0.f);
    out[idx] = f2bf(s);
}

// ---------------- heads slab-reduce + bias -> d_out (cls 128x84 | score 128x21) ----------------
__global__ void reduce_heads(const float* __restrict__ part, const float* __restrict__ bc,
                             const float* __restrict__ bsc, float* __restrict__ out) {
    const int idx = blockIdx.x * 256 + threadIdx.x;
    if (idx >= 128 * 105) return;
    const int m = idx / 105, n = idx % 105;
    float s = 0.f;
    for (int sl = 0; sl < 32; sl++) s += part[sl * (128 * 128) + m * 128 + n];
    if (n < 84) out[m * 84 + n] = s + bc[n];
    else out[128 * 84 + m * 21 + (n - 84)] = s + bsc[n - 84];
}

extern "C" void kernel_launch(void* const* d_in, const int* in_sizes, int n_in,
                              void* d_out, int out_size, void* d_ws, size_t ws_size,
                              hipStream_t stream) {
    const float* x    = (const float*)d_in[0];
    const float* rois = (const float*)d_in[1];
    const int*   ridx = (const int*)d_in[2];
    const float* w6   = (const float*)d_in[3];
    const float* b6   = (const float*)d_in[4];
    const float* w7   = (const float*)d_in[5];
    const float* b7   = (const float*)d_in[6];
    const float* wc   = (const float*)d_in[7];
    const float* bc   = (const float*)d_in[8];
    const float* wsc  = (const float*)d_in[9];
    const float* bsc  = (const float*)d_in[10];
    float* out = (float*)d_out;

    char* base = (char*)d_ws;
    short* Apool = (short*)base;                         // 128*25088*2 = 6,422,528 B
    float* whd   = (float*)(base + 6422528);             // 4096*128*4  = 2,097,152 B
    short* fc6b  = (short*)(base + 8519680);             // 128*4096*2  = 1,048,576 B
    short* fc7b  = (short*)(base + 9568256);             // 128*4096*2  = 1,048,576 B
    float* slabs = (float*)(base + 10616832);            // nslabs*128*4096*4 each
    const size_t slab_base = 10616832;
    const size_t slab_bytes = (size_t)128 * 4096 * 4;    // 2 MB per slab

    // Slab counts need even steps >= 4: 25088/28=896 (28 st), /14=1792 (56),
    // /8=3136 (98). Gated on ws_size with fallback.
    int ns6 = 8, ks6 = 3136;
    if (ws_size >= slab_base + 28 * slab_bytes)      { ns6 = 28; ks6 = 896; }
    else if (ws_size >= slab_base + 14 * slab_bytes) { ns6 = 14; ks6 = 1792; }
    int ns7 = 8, ks7 = 512;
    if (ws_size >= slab_base + 16 * slab_bytes)      { ns7 = 16; ks7 = 256; }

    pool_kernel<<<dim3(128, 8), 256, 0, stream>>>(x, rois, ridx, Apool);
    build_whd<<<2048, 256, 0, stream>>>(wc, wsc, whd);

    // fc6: K=25088, N=4096, 32 n-blocks of TN=128
    gemm128<<<dim3(32, ns6), 512, 0, stream>>>(Apool, w6, slabs, 25088, 4096, ks6);
    reduce_fc<<<2048, 256, 0, stream>>>(slabs, b6, fc6b, 4096, ns6);

    // fc7: K=4096, N=4096
    gemm128<<<dim3(32, ns7), 512, 0, stream>>>(fc6b, w7, slabs, 4096, 4096, ks7);
    reduce_fc<<<2048, 256, 0, stream>>>(slabs, b7, fc7b, 4096, ns7);

    // heads: K=4096, N=128 (1 n-block), 32 k-slabs (kchunk 128 -> 4 steps)
    gemm128<<<dim3(1, 32), 512, 0, stream>>>(fc7b, whd, slabs, 4096, 128, 128);
    reduce_heads<<<53, 256, 0, stream>>>(slabs, bc, bsc, out);
}